// Round 8
// baseline (197.578 us; speedup 1.0000x reference)
//
#include <hip/hip_runtime.h>
#include <hip/hip_bf16.h>

#define NDIM  64
#define BP    72
#define DT_   0.01f

typedef __attribute__((ext_vector_type(8)))  short bf16x8;
typedef __attribute__((ext_vector_type(16))) float f32x16;

// full-matrix fragment set: f[rb][j] -> lane(ln,hq) holds M[32*rb+ln][16*j+8*hq+0..7]
struct OpF { bf16x8 f[2][4]; };

// ---------------- bf16 helpers ----------------

__device__ __forceinline__ unsigned short f2b(float x) {
    __hip_bfloat16 h = __float2bfloat16(x);          // RTNE
    return __builtin_bit_cast(unsigned short, h);
}
__device__ __forceinline__ float b2f(unsigned short u) {
    unsigned int v = (unsigned int)u << 16;
    return __builtin_bit_cast(float, v);
}
__device__ __forceinline__ unsigned int f2b2(float lo, float hi) {
    return (unsigned int)f2b(lo) | ((unsigned int)f2b(hi) << 16);
}

// ---------------- fragment loads ----------------

__device__ __forceinline__ void ld_ws_op(OpF& F, const unsigned short* __restrict__ p,
                                         int ln, int hq) {
#pragma unroll
    for (int rb = 0; rb < 2; ++rb)
#pragma unroll
        for (int j = 0; j < 4; ++j)
            F.f[rb][j] = *(const bf16x8*)&p[(32 * rb + ln) * 64 + j * 16 + hq * 8];
}

__device__ __forceinline__ void ld_rho(OpF& F, const float* __restrict__ p, int ln, int hq) {
#pragma unroll
    for (int rb = 0; rb < 2; ++rb)
#pragma unroll
        for (int j = 0; j < 4; ++j) {
            const float* q = &p[(32 * rb + ln) * 64 + j * 16 + hq * 8];
            float4 u = *(const float4*)q;
            float4 v = *(const float4*)(q + 4);
            uint4 o;
            o.x = f2b2(u.x, u.y); o.y = f2b2(u.z, u.w);
            o.z = f2b2(v.x, v.y); o.w = f2b2(v.z, v.w);
            F.f[rb][j] = __builtin_bit_cast(bf16x8, o);
        }
}

// ---------------- full-register NT gemm: C = A @ B^T (16 MFMA) ----------------

template <bool ACC>
__device__ __forceinline__ void gemmR(f32x16 (&C)[2][2], const OpF& A, const OpF& B) {
    if (!ACC) {
#pragma unroll
        for (int qr = 0; qr < 2; ++qr)
#pragma unroll
            for (int qc = 0; qc < 2; ++qc)
#pragma unroll
                for (int r = 0; r < 16; ++r) C[qr][qc][r] = 0.f;
    }
#pragma unroll
    for (int j = 0; j < 4; ++j)
#pragma unroll
        for (int qr = 0; qr < 2; ++qr)
#pragma unroll
            for (int qc = 0; qc < 2; ++qc)
                C[qr][qc] = __builtin_amdgcn_mfma_f32_32x32x16_bf16(
                    A.f[qr][j], B.f[qc][j], C[qr][qc], 0, 0, 0);
}

// ---------------- in-register slot -> frag transpose (C slots of P -> frags of P^T) ------
// slot r: row = (r&3)+8*(r>>2)+4*hq, col = ln.  Target frag (rb=qc, j=2*qr+t) of lane
// (ln,hq): k=16j+8hq+e -> own group g=2t+hq (e0..3) + partner's same group (e4..7),
// exchanged via one shfl_xor(32) of the hq-dependent send group g=2t+1-hq.

__device__ __forceinline__ void convQ(const f32x16& c, int hq, bf16x8& fe, bf16x8& fo) {
    unsigned pk[4][2];
#pragma unroll
    for (int g = 0; g < 4; ++g) {
        pk[g][0] = f2b2(c[4 * g + 0], c[4 * g + 1]);
        pk[g][1] = f2b2(c[4 * g + 2], c[4 * g + 3]);
    }
#pragma unroll
    for (int t = 0; t < 2; ++t) {
        unsigned o0 = hq ? pk[2 * t + 1][0] : pk[2 * t][0];
        unsigned o1 = hq ? pk[2 * t + 1][1] : pk[2 * t][1];
        unsigned s0 = hq ? pk[2 * t][0]     : pk[2 * t + 1][0];
        unsigned s1 = hq ? pk[2 * t][1]     : pk[2 * t + 1][1];
        unsigned r0 = (unsigned)__shfl_xor((int)s0, 32, 64);
        unsigned r1 = (unsigned)__shfl_xor((int)s1, 32, 64);
        uint4 u;
        u.x = hq ? r0 : o0;
        u.y = hq ? r1 : o1;
        u.z = hq ? o0 : r0;
        u.w = hq ? o1 : r1;
        bf16x8 f = __builtin_bit_cast(bf16x8, u);
        if (t == 0) fe = f; else fo = f;
    }
}

__device__ __forceinline__ void convF(const f32x16 (&C)[2][2], OpF& F, int hq) {
#pragma unroll
    for (int qr = 0; qr < 2; ++qr)
#pragma unroll
        for (int qc = 0; qc < 2; ++qc)
            convQ(C[qr][qc], hq, F.f[qc][2 * qr + 0], F.f[qc][2 * qr + 1]);
}

// ---------------- frag-space linear combos ----------------

__device__ __forceinline__ bf16x8 comb2(bf16x8 a, bf16x8 b, float cb) {
    bf16x8 r;
#pragma unroll
    for (int e = 0; e < 8; e += 2) {
        float f0 = b2f((unsigned short)a[e])     + cb * b2f((unsigned short)b[e]);
        float f1 = b2f((unsigned short)a[e + 1]) + cb * b2f((unsigned short)b[e + 1]);
        unsigned pkv = f2b2(f0, f1);
        r[e] = (short)(pkv & 0xffffu); r[e + 1] = (short)(pkv >> 16);
    }
    return r;
}
__device__ __forceinline__ bf16x8 comb3(bf16x8 a, bf16x8 b, bf16x8 c, float cb, float cc) {
    bf16x8 r;
#pragma unroll
    for (int e = 0; e < 8; e += 2) {
        float f0 = b2f((unsigned short)a[e]) + cb * b2f((unsigned short)b[e])
                 + cc * b2f((unsigned short)c[e]);
        float f1 = b2f((unsigned short)a[e + 1]) + cb * b2f((unsigned short)b[e + 1])
                 + cc * b2f((unsigned short)c[e + 1]);
        unsigned pkv = f2b2(f0, f1);
        r[e] = (short)(pkv & 0xffffu); r[e + 1] = (short)(pkv >> 16);
    }
    return r;
}

// ---------------- wave-private LDS park (no barriers: per-wave DS is in-order) ----------

__device__ __forceinline__ void park_st(unsigned short* base, const OpF& F, int lane) {
#pragma unroll
    for (int f = 0; f < 8; ++f)
        *(uint4*)&base[(f * 64 + lane) * 8] = __builtin_bit_cast(uint4, F.f[f >> 2][f & 3]);
}
__device__ __forceinline__ void park_ld(OpF& F, const unsigned short* base, int lane) {
#pragma unroll
    for (int f = 0; f < 8; ++f)
        F.f[f >> 2][f & 3] = __builtin_bit_cast(bf16x8,
            *(const uint4*)&base[(f * 64 + lane) * 8]);
}

// ---------------- setup: 11 blocks ----------------
// ws (bf16, 4096 each): 0=Uh 1=U1 2=L00 3=L01 4=Lh0 5=Lh1 6=L10 7=L11 8=V 9=c16*L10 10=c16*L11

__global__ void __launch_bounds__(256) krk_setup(const float* __restrict__ Uh,
                                                 const float* __restrict__ U1,
                                                 const float* __restrict__ L0,
                                                 const float* __restrict__ Lh,
                                                 const float* __restrict__ L1,
                                                 unsigned short* __restrict__ ws) {
    __shared__ unsigned short sW [NDIM * BP];
    __shared__ unsigned short sWt[NDIM * BP];

    const int blk = blockIdx.x, tid = threadIdx.x;
    const float c16 = DT_ / 6.f;

    if (blk < 8) {
        const float* srcs[8] = {Uh, U1, L0, L0 + 4096, Lh, Lh + 4096, L1, L1 + 4096};
        const float* s = srcs[blk];
        unsigned short* d = ws + blk * 4096;
#pragma unroll
        for (int i = 0; i < 4; ++i) {
            int flat = (tid + i * 256) * 4;
            float4 v = *(const float4*)&s[flat];
            uint2 o; o.x = f2b2(v.x, v.y); o.y = f2b2(v.z, v.w);
            *(uint2*)&d[flat] = o;
        }
        return;
    }
    if (blk >= 9) {
        const float* s = (blk == 9) ? L1 : L1 + 4096;
        unsigned short* d = ws + blk * 4096;
#pragma unroll
        for (int i = 0; i < 4; ++i) {
            int flat = (tid + i * 256) * 4;
            float4 v = *(const float4*)&s[flat];
            uint2 o; o.x = f2b2(c16 * v.x, c16 * v.y); o.y = f2b2(c16 * v.z, c16 * v.w);
            *(uint2*)&d[flat] = o;
        }
        return;
    }

    // ---- block 8: V = I + W + W^2  (W = I - Uh), row-major bf16
    const int lane = tid & 63, w = tid >> 6, ln = lane & 31, hq = lane >> 5;
    const int rw = 32 * (w >> 1), cw = 32 * (w & 1);

#pragma unroll
    for (int i = 0; i < 4; ++i) {
        int flat = (tid + i * 256) * 4;
        int r = flat >> 6, c = flat & 63;
        float4 u = *(const float4*)&Uh[flat];
        float wv[4] = {-u.x, -u.y, -u.z, -u.w};
#pragma unroll
        for (int j = 0; j < 4; ++j)
            if (r == c + j) wv[j] += 1.f;
        unsigned short o[4] = {f2b(wv[0]), f2b(wv[1]), f2b(wv[2]), f2b(wv[3])};
        *(uint2*)&sW[r * BP + c] = *(uint2*)o;
#pragma unroll
        for (int j = 0; j < 4; ++j) sWt[(c + j) * BP + r] = o[j];
    }
    bf16x8 Fw[4];
    {
        const int n = cw + ln;
#pragma unroll
        for (int j = 0; j < 4; ++j) {
            const int k0 = j * 16 + hq * 8;
            const float* q = &Uh[n * 64 + k0];
            float4 u = *(const float4*)q;
            float4 v = *(const float4*)(q + 4);
            float wv[8] = {-u.x, -u.y, -u.z, -u.w, -v.x, -v.y, -v.z, -v.w};
#pragma unroll
            for (int e = 0; e < 8; ++e)
                if (n == k0 + e) wv[e] += 1.f;
            uint4 o;
            o.x = f2b2(wv[0], wv[1]); o.y = f2b2(wv[2], wv[3]);
            o.z = f2b2(wv[4], wv[5]); o.w = f2b2(wv[6], wv[7]);
            Fw[j] = __builtin_bit_cast(bf16x8, o);
        }
    }
    __syncthreads();

    f32x16 t0;
#pragma unroll
    for (int r = 0; r < 16; ++r) t0[r] = 0.f;
#pragma unroll
    for (int j = 0; j < 4; ++j)
        t0 = __builtin_amdgcn_mfma_f32_32x32x16_bf16(
            *(const bf16x8*)&sWt[(rw + ln) * BP + j * 16 + hq * 8], Fw[j], t0, 0, 0, 0);
    float wts[16];
#pragma unroll
    for (int g = 0; g < 4; ++g) {
        uint2 u = *(const uint2*)&sW[(cw + ln) * BP + rw + 8 * g + 4 * hq];
        unsigned short o[4]; *(uint2*)o = u;
#pragma unroll
        for (int j = 0; j < 4; ++j) wts[4 * g + j] = b2f(o[j]);
    }
    unsigned short* ws8 = ws + 8 * 4096;
#pragma unroll
    for (int g = 0; g < 4; ++g) {
        uint2 o;
#pragma unroll
        for (int j = 0; j < 4; j += 2) {
            int r0 = 4 * g + j, r1 = r0 + 1;
            int row0 = rw + (r0 & 3) + 8 * g + 4 * hq;
            float v0 = ((row0 == cw + ln) ? 1.f : 0.f) + wts[r0] + t0[r0];
            float v1 = ((row0 + 1 == cw + ln) ? 1.f : 0.f) + wts[r1] + t0[r1];
            if (j == 0) o.x = f2b2(v0, v1); else o.y = f2b2(v0, v1);
        }
        *(uint2*)&ws8[(cw + ln) * 64 + rw + 8 * g + 4 * hq] = o;
    }
}

// ---------------- main: one WAVE per matrix, zero barriers, register-resident chain -------

__global__ void __launch_bounds__(256, 2) krk_main(const float* __restrict__ rho0,
                                                   const unsigned short* __restrict__ ws,
                                                   float* __restrict__ out) {
    __shared__ unsigned short PK[4][2][4096];        // per-wave parks: rho, S0 (64 KB)

    const int tid = threadIdx.x;
    const int wv = tid >> 6, lane = tid & 63, ln = lane & 31, hq = lane >> 5;
    const int mat = blockIdx.x * 4 + wv;
    const float* rho = rho0 + (size_t)mat * (NDIM * NDIM);

    const float c12 = 0.5f * DT_, c16 = DT_ / 6.f, c23 = 2.f * DT_ / 3.f;

    OpF Pf, Fa, Fb, Oa;
    f32x16 C[2][2], D[2][2], O[2][2];

    ld_rho(Pf, rho, ln, hq);                         // rho frags

    // ---- S0 = sum L0k rho L0k^T  (acc in D)
    ld_ws_op(Oa, ws + 2 * 4096, ln, hq);             // L00
    gemmR<false>(C, Pf, Oa); convF(C, Fa, hq);       // Fa = L00 rho
    gemmR<false>(D, Fa, Oa);
    ld_ws_op(Oa, ws + 3 * 4096, ln, hq);             // L01
    gemmR<false>(C, Pf, Oa); convF(C, Fa, hq);       // Fa = L01 rho
    gemmR<true >(D, Fa, Oa);
    convF(D, Fb, hq);                                // Fb = S0 frags

    // ---- X = rho + c12 S0 ; park rho, S0
    {
        OpF X;
#pragma unroll
        for (int rb = 0; rb < 2; ++rb)
#pragma unroll
            for (int j = 0; j < 4; ++j)
                X.f[rb][j] = comb2(Pf.f[rb][j], Fb.f[rb][j], c12);
        park_st(&PK[wv][0][0], Pf, lane);
        park_st(&PK[wv][1][0], Fb, lane);
        Fa = X;
    }

    // ---- rho1 = Uh X Uh^T
    ld_ws_op(Oa, ws + 0 * 4096, ln, hq);             // Uh
    gemmR<false>(C, Fa, Oa); convF(C, Fb, hq);       // Fb = Uh X
    gemmR<false>(C, Fb, Oa); convF(C, Fa, hq);       // Fa = rho1

    // ---- S1 (acc in D)
    ld_ws_op(Oa, ws + 4 * 4096, ln, hq);             // Lh0
    gemmR<false>(C, Fa, Oa); convF(C, Fb, hq);
    gemmR<false>(D, Fb, Oa);
    ld_ws_op(Oa, ws + 5 * 4096, ln, hq);             // Lh1
    gemmR<false>(C, Fa, Oa); convF(C, Fb, hq);
    gemmR<true >(D, Fb, Oa);
    convF(D, Fa, hq);                                // Fa = S1

    // ---- H1 = V S1 V^T
    ld_ws_op(Oa, ws + 8 * 4096, ln, hq);             // V
    gemmR<false>(C, Fa, Oa); convF(C, Fb, hq);       // Fb = V S1
    gemmR<false>(C, Fb, Oa); convF(C, Fb, hq);       // Fb = H1

    // ---- M1 -> Fa, M2 -> Pf (unpark rho, S0)
    {
        OpF S0t;
        park_ld(Pf, &PK[wv][0][0], lane);
        park_ld(S0t, &PK[wv][1][0], lane);
#pragma unroll
        for (int rb = 0; rb < 2; ++rb)
#pragma unroll
            for (int j = 0; j < 4; ++j) {
                Fa.f[rb][j] = comb3(Pf.f[rb][j], S0t.f[rb][j], Fb.f[rb][j], c16, c23);  // M1
                Pf.f[rb][j] = comb2(Pf.f[rb][j], Fb.f[rb][j], DT_);                     // M2
            }
    }

    // ---- a1 = U1 M1 U1^T (acc O) ; rho2 = U1 M2 U1^T
    ld_ws_op(Oa, ws + 1 * 4096, ln, hq);             // U1
    gemmR<false>(C, Fa, Oa); convF(C, Fa, hq);       // Fa = U1 M1
    gemmR<false>(O, Fa, Oa);                         // O = a1 slots
    gemmR<false>(C, Pf, Oa); convF(C, Fb, hq);       // Fb = U1 M2
    gemmR<false>(C, Fb, Oa); convF(C, Fa, hq);       // Fa = rho2

    // ---- O += sum (c16 L1k) rho2 L1k^T
    ld_ws_op(Oa, ws + 6 * 4096, ln, hq);             // L10
    gemmR<false>(C, Fa, Oa); convF(C, Fb, hq);       // Fb = L10 rho2
    ld_ws_op(Oa, ws + 9 * 4096, ln, hq);             // c16 L10
    gemmR<true >(O, Fb, Oa);
    ld_ws_op(Oa, ws + 7 * 4096, ln, hq);             // L11
    gemmR<false>(C, Fa, Oa); convF(C, Fb, hq);       // Fb = L11 rho2
    ld_ws_op(Oa, ws + 10 * 4096, ln, hq);            // c16 L11
    gemmR<true >(O, Fb, Oa);

    // ---- store (out symmetric -> transposed store exact; float4)
    float* o = out + (size_t)mat * (NDIM * NDIM);
#pragma unroll
    for (int qc = 0; qc < 2; ++qc)
#pragma unroll
        for (int qr = 0; qr < 2; ++qr)
#pragma unroll
            for (int g = 0; g < 4; ++g) {
                float4 v;
                v.x = O[qr][qc][4 * g + 0];
                v.y = O[qr][qc][4 * g + 1];
                v.z = O[qr][qc][4 * g + 2];
                v.w = O[qr][qc][4 * g + 3];
                *(float4*)&o[(32 * qc + ln) * 64 + 32 * qr + 8 * g + 4 * hq] = v;
            }
}

// ---------------- host launch ----------------

extern "C" void kernel_launch(void* const* d_in, const int* in_sizes, int n_in,
                              void* d_out, int out_size, void* d_ws, size_t ws_size,
                              hipStream_t stream) {
    const float* rho0 = (const float*)d_in[0];
    const float* Uh   = (const float*)d_in[1];
    const float* U1   = (const float*)d_in[2];
    const float* L0   = (const float*)d_in[3];
    const float* Lh   = (const float*)d_in[4];
    const float* L1   = (const float*)d_in[5];
    float* out = (float*)d_out;
    unsigned short* ws = (unsigned short*)d_ws;      // 11 bf16 64x64 matrices

    int Bn = in_sizes[0] / (NDIM * NDIM);            // 4096

    krk_setup<<<11, 256, 0, stream>>>(Uh, U1, L0, Lh, L1, ws);
    krk_main<<<Bn / 4, 256, 0, stream>>>(rho0, ws, out);
}